// Round 3
// baseline (2036.553 us; speedup 1.0000x reference)
//
#include <hip/hip_runtime.h>
#include <stdint.h>

#define B_  8
#define S_  8192
#define D_  512
#define NB_ 16
#define M_  (B_*S_)   // 65536 rows

typedef short bf16x8 __attribute__((ext_vector_type(8)));
typedef float f32x4  __attribute__((ext_vector_type(4)));

static __device__ __forceinline__ unsigned short f2bf(float f) {
  unsigned int u = __float_as_uint(f);
  u += 0x7fff + ((u >> 16) & 1);   // RNE
  return (unsigned short)(u >> 16);
}

// async global->LDS, 16B per lane. LDS dest is wave-uniform base + lane*16.
static __device__ __forceinline__ void async_copy16(const unsigned short* g,
                                                    unsigned short* l) {
  auto* g1 = reinterpret_cast<const __attribute__((address_space(1))) uint32_t*>(
      reinterpret_cast<uintptr_t>(g));
  auto* l3 = reinterpret_cast<__attribute__((address_space(3))) uint32_t*>(
      reinterpret_cast<uintptr_t>(l));
  __builtin_amdgcn_global_load_lds(g1, l3, 16, 0, 0);
}

__global__ __launch_bounds__(256) void zero_kernel(float* p, int n) {
  int i = blockIdx.x * 256 + threadIdx.x;
  if (i < n) p[i] = 0.f;
}

// Column mean accumulate: acc[b*D+d] += sum_{s in block chunk} x[b][s][d]
__global__ __launch_bounds__(512) void colmean_kernel(const float* __restrict__ x,
                                                      float* __restrict__ acc) {
  int b = blockIdx.x, d = threadIdx.x;
  const float* p = x + ((size_t)b * S_ + (size_t)blockIdx.y * 512) * D_ + d;
  float s = 0.f;
  #pragma unroll 8
  for (int i = 0; i < 512; i++) s += p[(size_t)i * D_];
  atomicAdd(&acc[b * D_ + d], s);
}

// wave0: embodied selector, wave1: disembodied. out[0..1]=emb top2, out[2..3]=dis top2
__global__ __launch_bounds__(128) void top2_kernel(const float* __restrict__ embAcc,
                                                   const float* __restrict__ embW,
                                                   const float* __restrict__ embB,
                                                   const float* __restrict__ disAcc,
                                                   const float* __restrict__ disW,
                                                   const float* __restrict__ disB,
                                                   int* __restrict__ out) {
  int wave = threadIdx.x >> 6, lane = threadIdx.x & 63;
  const float* acc = wave ? disAcc : embAcc;
  const float* W   = wave ? disW   : embW;
  const float* bb  = wave ? disB   : embB;
  const float invS = 1.f / (float)S_;
  float logit[NB_];
  for (int nb = 0; nb < NB_; nb++) {
    float s = 0.f;
    for (int d = lane; d < D_; d += 64) s += acc[d] * invS * W[d * NB_ + nb];
    for (int o = 32; o; o >>= 1) s += __shfl_xor(s, o);
    logit[nb] = s + bb[nb];
  }
  if (lane == 0) {
    int i0 = 0;
    for (int i = 1; i < NB_; i++) if (logit[i] > logit[i0]) i0 = i;
    int i1 = (i0 == 0) ? 1 : 0;
    for (int i = 0; i < NB_; i++) if (i != i0 && logit[i] > logit[i1]) i1 = i;
    out[wave * 2 + 0] = i0;
    out[wave * 2 + 1] = i1;
  }
}

// LayerNorm (dynamic block idx for gamma/beta) + cast to bf16. One wave per row.
__global__ __launch_bounds__(256) void ln_cast_kernel(const float* __restrict__ x,
                                                      const float* __restrict__ gB,
                                                      const float* __restrict__ bB,
                                                      const int* __restrict__ idxPtr,
                                                      unsigned short* __restrict__ out) {
  int row  = blockIdx.x * 4 + (threadIdx.x >> 6);
  int lane = threadIdx.x & 63;
  const float4* xr = (const float4*)(x + (size_t)row * D_ + lane * 8);
  float4 v0 = xr[0], v1 = xr[1];
  float s  = v0.x + v0.y + v0.z + v0.w + v1.x + v1.y + v1.z + v1.w;
  float sq = v0.x*v0.x + v0.y*v0.y + v0.z*v0.z + v0.w*v0.w
           + v1.x*v1.x + v1.y*v1.y + v1.z*v1.z + v1.w*v1.w;
  for (int o = 32; o; o >>= 1) { s += __shfl_xor(s, o); sq += __shfl_xor(sq, o); }
  float mean = s * (1.f / D_);
  float var  = sq * (1.f / D_) - mean * mean;
  float rstd = rsqrtf(var + 1e-5f);
  int idx = *idxPtr;
  const float4* g4 = (const float4*)(gB + (size_t)idx * D_ + lane * 8);
  const float4* b4 = (const float4*)(bB + (size_t)idx * D_ + lane * 8);
  float4 g0 = g4[0], g1 = g4[1], c0 = b4[0], c1 = b4[1];
  float xv[8] = {v0.x, v0.y, v0.z, v0.w, v1.x, v1.y, v1.z, v1.w};
  float gv[8] = {g0.x, g0.y, g0.z, g0.w, g1.x, g1.y, g1.z, g1.w};
  float bv[8] = {c0.x, c0.y, c0.z, c0.w, c1.x, c1.y, c1.z, c1.w};
  unsigned short o8[8] __attribute__((aligned(16)));
  #pragma unroll
  for (int k = 0; k < 8; k++) o8[k] = f2bf((xv[k] - mean) * rstd * gv[k] + bv[k]);
  *(uint4*)(out + (size_t)row * D_ + lane * 8) = *(const uint4*)o8;
}

// Gather selected block's weight [K,N] f32 -> transposed bf16 dst[N][K] (LDS tiled)
__global__ __launch_bounds__(256) void wconvert_kernel(const float* __restrict__ srcAll,
                                                       const int* __restrict__ idxPtr,
                                                       int K, int N,
                                                       unsigned short* __restrict__ dst) {
  __shared__ float t[32][33];
  int idx = *idxPtr;
  const float* src = srcAll + (size_t)idx * K * N;
  int k0 = blockIdx.y * 32, n0 = blockIdx.x * 32;
  int tid = threadIdx.x;
  int kl = tid >> 5, nl = tid & 31;  // kl in 0..7
  #pragma unroll
  for (int r = 0; r < 4; r++)
    t[kl + r * 8][nl] = src[(size_t)(k0 + kl + r * 8) * N + n0 + nl];
  __syncthreads();
  #pragma unroll
  for (int r = 0; r < 4; r++)
    dst[(size_t)(n0 + kl + r * 8) * K + k0 + nl] = f2bf(t[nl][kl + r * 8]);
}

// ---------------------------------------------------------------------------
// 256x256 / BK=32 / 8-wave / 4-deep-ring GEMM (R2 structure) for the two
// epilogues that need no LayerNorm: EPI 0 (emb gemm1, tanh->bf16) and
// EPI 3 (dis ff1, gelu->bf16).
template<int EPI>
__global__ __launch_bounds__(512, 2) void gemm_kernel(const unsigned short* __restrict__ A,
                                                      const unsigned short* __restrict__ Bt,
                                                      int K, int N,
                                                      const int* __restrict__ idxPtr,
                                                      const float* __restrict__ biasBase,
                                                      unsigned short* __restrict__ bout) {
  __shared__ __align__(16) unsigned short lds[4][2][8192];  // [buf][A|B][256 rows x 32 cols]
  const int tid  = threadIdx.x;
  const int wid  = tid >> 6, lane = tid & 63;
  const int quad = lane >> 4, l16 = lane & 15;
  const int wr = wid >> 2, wc = wid & 3;        // wave -> (2M x 4N) sub-tile

  const int nT  = N >> 8;                        // 2 or 4 n-tiles
  const int lgn = (nT == 2) ? 1 : 2;
  const int perX = gridDim.x >> 3;
  const int tile = ((int)blockIdx.x & 7) * perX + ((int)blockIdx.x >> 3);
  const int m0 = (tile >> lgn) << 8;
  const int n0 = (tile & (nT - 1)) << 8;

  // staging: thread t covers 16B of row t/4 (per 128-row half). HW writes LDS
  // linearly at slot (t&3); fetch logical K-segment (t&3)^sw(row), sw(r)=(r>>1)&3.
  const int srow = tid >> 2;
  const int scol = (((tid & 3) ^ ((tid >> 3) & 3)) * 8);
  const unsigned short* Ag0 = A  + (size_t)(m0 + srow) * K + scol;
  const unsigned short* Ag1 = Ag0 + (size_t)128 * K;
  const unsigned short* Bg0 = Bt + (size_t)(n0 + srow) * K + scol;
  const unsigned short* Bg1 = Bg0 + (size_t)128 * K;

  auto stageA = [&](int kt, int b) {
    async_copy16(Ag0 + (size_t)kt * 32, &lds[b][0][tid * 8]);
    async_copy16(Ag1 + (size_t)kt * 32, &lds[b][0][4096 + tid * 8]);
  };
  auto stageB = [&](int kt, int b) {
    async_copy16(Bg0 + (size_t)kt * 32, &lds[b][1][tid * 8]);
    async_copy16(Bg1 + (size_t)kt * 32, &lds[b][1][4096 + tid * 8]);
  };

  f32x4 acc[8][4] = {};
  const int nK = K >> 5;

  stageA(0, 0); stageB(0, 0);
  stageA(1, 1); stageB(1, 1);
  stageA(2, 2); stageB(2, 2);

  const int rsw  = (l16 >> 1) & 3;
  const int aoff = (wr * 128 + l16) * 32 + ((quad ^ rsw) * 8);
  const int boff = (wc * 64  + l16) * 32 + ((quad ^ rsw) * 8);

  for (int k = 0; k < nK; ++k) {
    const int cur = k & 3;
    const int nxt = (k + 3) & 3;
    const int kn  = (k + 3 < nK) ? (k + 3) : 0;
    stageA(kn, nxt);
    asm volatile("s_waitcnt vmcnt(10)" ::: "memory");
    asm volatile("s_barrier" ::: "memory");

    const unsigned short* Ab = &lds[cur][0][aoff];
    const unsigned short* Bb = &lds[cur][1][boff];
    bf16x8 af[4], bfr[4];
    #pragma unroll
    for (int i = 0; i < 4; ++i) af[i]  = *(const bf16x8*)(Ab + i * 512);
    #pragma unroll
    for (int j = 0; j < 4; ++j) bfr[j] = *(const bf16x8*)(Bb + j * 512);
    __builtin_amdgcn_s_setprio(1);
    #pragma unroll
    for (int i = 0; i < 4; ++i)
      #pragma unroll
      for (int j = 0; j < 4; ++j)
        acc[i][j] = __builtin_amdgcn_mfma_f32_16x16x32_bf16(af[i], bfr[j], acc[i][j], 0, 0, 0);
    __builtin_amdgcn_s_setprio(0);

    stageB(kn, nxt);
    #pragma unroll
    for (int i = 0; i < 4; ++i) af[i] = *(const bf16x8*)(Ab + (64 + i * 16) * 32);
    __builtin_amdgcn_s_setprio(1);
    #pragma unroll
    for (int i = 0; i < 4; ++i)
      #pragma unroll
      for (int j = 0; j < 4; ++j)
        acc[4 + i][j] = __builtin_amdgcn_mfma_f32_16x16x32_bf16(af[i], bfr[j], acc[4 + i][j], 0, 0, 0);
    __builtin_amdgcn_s_setprio(0);
    asm volatile("s_barrier" ::: "memory");
  }

  const int idx = *idxPtr;
  const float* bias = biasBase + (size_t)idx * N;
  #pragma unroll
  for (int mf = 0; mf < 8; ++mf) {
    int rowb = m0 + wr * 128 + mf * 16 + quad * 4;
    #pragma unroll
    for (int nf = 0; nf < 4; ++nf) {
      int col = n0 + wc * 64 + nf * 16 + l16;
      float bc = bias[col];
      #pragma unroll
      for (int r = 0; r < 4; ++r) {
        size_t off = (size_t)(rowb + r) * N + col;
        float v = acc[mf][nf][r] + bc;
        if constexpr (EPI == 0) {
          bout[off] = f2bf(tanhf(v));
        } else {
          float gl = 0.5f * v * (1.f + erff(v * 0.70710678118654752f));
          bout[off] = f2bf(gl);
        }
      }
    }
  }
  asm volatile("s_waitcnt vmcnt(0)" ::: "memory");
}

// ---------------------------------------------------------------------------
// R3: LN-fused GEMM. Tile 128(M) x 512(N = full row) so the epilogue can do
// the NEXT layer's LayerNorm in-place: f32 result -> fout (residual/output)
// AND row-stats -> normalized bf16 -> aout (next GEMM's A). Removes the 134MB
// f32 re-read + a full dispatch per fusion site (4 sites).
// K-loop: R2's ring(+swizzle) at depth 3 (A 8KB + B 32KB per tile = 40KB;
// 3x40 + 4KB partials = 124KB LDS). 5 loads/tile/wave -> vmcnt(10) = tile-k done.
// Waves 2Mx4N: per-wave 64 rows x 128 cols, acc[4][8] f32x4.
// EPI 1: res = hin + (acc+bias)*(1+0.1*torsion)*0.3          (emb gemm2)
// EPI 2: res = hin + 0.5*((acc+bias+0.2*delayed)*(1+0.05*torsion))  (dis attn)
// EPI 4: res = hin + 0.5*(acc+bias)                          (dis ff2)
template<int EPI, bool DO_LN>
__global__ __launch_bounds__(512, 2) void gemm_ln_kernel(const unsigned short* __restrict__ A,
                                                         const unsigned short* __restrict__ Bt,
                                                         int K,
                                                         const int* __restrict__ idxPtr,
                                                         const float* __restrict__ biasBase,
                                                         const float* __restrict__ hin,
                                                         float* __restrict__ fout,
                                                         const float* __restrict__ torsion,
                                                         const float* __restrict__ dAcc,
                                                         const float* __restrict__ lnG,
                                                         const float* __restrict__ lnB,
                                                         const int* __restrict__ lnIdxPtr,
                                                         unsigned short* __restrict__ aout) {
  __shared__ __align__(16) unsigned short ring[3][20480];  // A[0,8KB) + B[8KB,40KB) per slot
  __shared__ float psum[128][4];
  __shared__ float psq[128][4];
  const int tid  = threadIdx.x;
  const int wid  = tid >> 6, lane = tid & 63;
  const int quad = lane >> 4, l16 = lane & 15;
  const int wr = wid >> 2, wc = wid & 3;     // 2M x 4N waves; wave = 64 rows x 128 cols

  // XCD-aware: consecutive M-tiles per XCD (grid 512, %8==0)
  const int perX = gridDim.x >> 3;
  const int tile = ((int)blockIdx.x & 7) * perX + ((int)blockIdx.x >> 3);
  const int m0 = tile << 7;                  // 128-row tile, full 512-col width

  // staging: thread t -> row t/4, physical slot t&3 holds logical seg (t&3)^sw(row),
  // sw(r) = (r>>1)&3 -> ((t>>3)&3). A: 1 instr (8KB); B: 4 instrs (32KB, 512 rows).
  const int srow = tid >> 2;
  const int scol = (((tid & 3) ^ ((tid >> 3) & 3)) * 8);
  const unsigned short* Ag = A  + (size_t)(m0 + srow) * K + scol;
  const unsigned short* Bg = Bt + (size_t)srow * K + scol;

  auto stage = [&](int kt, int slot) {
    unsigned short* base = &ring[slot][0];
    async_copy16(Ag + (size_t)kt * 32, base + tid * 8);
    #pragma unroll
    for (int j = 0; j < 4; ++j)
      async_copy16(Bg + (size_t)(j * 128) * K + (size_t)kt * 32,
                   base + 4096 + j * 4096 + tid * 8);
  };

  f32x4 acc[4][8] = {};
  const int nK = K >> 5;

  stage(0, 0);
  stage(1, 1);

  const int rsw  = (l16 >> 1) & 3;
  const int aoff = (wr * 64  + l16) * 32 + ((quad ^ rsw) * 8);
  const int boff = 4096 + (wc * 128 + l16) * 32 + ((quad ^ rsw) * 8);

  for (int k = 0; k < nK; ++k) {
    const int cur = k % 3;
    const int nxt = (k + 2) % 3;
    const int kn  = (k + 2 < nK) ? (k + 2) : 0;
    stage(kn, nxt);
    // outstanding newer than tile k: tile k+1 (5) + tile k+2 (5) = 10
    asm volatile("s_waitcnt vmcnt(10)" ::: "memory");
    asm volatile("s_barrier" ::: "memory");

    const unsigned short* Ab = &ring[cur][aoff];
    const unsigned short* Bb = &ring[cur][boff];
    bf16x8 af[4], bfr[8];
    #pragma unroll
    for (int i = 0; i < 4; ++i) af[i]  = *(const bf16x8*)(Ab + i * 512);
    #pragma unroll
    for (int j = 0; j < 8; ++j) bfr[j] = *(const bf16x8*)(Bb + j * 512);
    __builtin_amdgcn_s_setprio(1);
    #pragma unroll
    for (int i = 0; i < 4; ++i)
      #pragma unroll
      for (int j = 0; j < 8; ++j)
        acc[i][j] = __builtin_amdgcn_mfma_f32_16x16x32_bf16(af[i], bfr[j], acc[i][j], 0, 0, 0);
    __builtin_amdgcn_s_setprio(0);
    asm volatile("s_barrier" ::: "memory");   // reads of buf[cur] done
  }

  // ---- epilogue: res(f32)->fout, and (optionally) row-LN -> bf16 aout
  const int idx = *idxPtr;
  const float* bias = biasBase + (size_t)idx * 512;
  const int bcn = m0 >> 13;                   // batch index, uniform per block
  const float invS = 1.f / (float)S_;
  float bc[8], tv[8], dv[8];
  #pragma unroll
  for (int nf = 0; nf < 8; ++nf) {
    int col = wc * 128 + nf * 16 + l16;
    bc[nf] = bias[col];
    if constexpr (EPI == 1) tv[nf] = 1.f + 0.1f  * torsion[bcn * D_ + col];
    if constexpr (EPI == 2) tv[nf] = 1.f + 0.05f * torsion[bcn * D_ + col];
    if constexpr (EPI == 2) dv[nf] = 0.2f * dAcc[bcn * D_ + col] * invS;
  }
  #pragma unroll
  for (int mf = 0; mf < 4; ++mf) {
    #pragma unroll
    for (int r = 0; r < 4; ++r) {
      int rowl = wr * 64 + mf * 16 + quad * 4 + r;
      size_t rbase = (size_t)(m0 + rowl) * 512;
      float s = 0.f, sq = 0.f;
      #pragma unroll
      for (int nf = 0; nf < 8; ++nf) {
        int col = wc * 128 + nf * 16 + l16;
        float v = acc[mf][nf][r] + bc[nf];
        float res;
        if constexpr (EPI == 1) {
          res = hin[rbase + col] + v * tv[nf] * 0.3f;
        } else if constexpr (EPI == 2) {
          res = hin[rbase + col] + 0.5f * ((v + dv[nf]) * tv[nf]);
        } else {
          res = hin[rbase + col] + 0.5f * v;
        }
        fout[rbase + col] = res;
        acc[mf][nf][r] = res;                 // keep for LN
        s += res; sq += res * res;
      }
      if constexpr (DO_LN) {
        #pragma unroll
        for (int o = 1; o < 16; o <<= 1) { s += __shfl_xor(s, o); sq += __shfl_xor(sq, o); }
        if (l16 == 0) { psum[rowl][wc] = s; psq[rowl][wc] = sq; }
      }
    }
  }
  if constexpr (DO_LN) {
    __syncthreads();
    const int li = *lnIdxPtr;
    float gv[8], bv[8];
    #pragma unroll
    for (int nf = 0; nf < 8; ++nf) {
      int col = wc * 128 + nf * 16 + l16;
      gv[nf] = lnG[(size_t)li * D_ + col];
      bv[nf] = lnB[(size_t)li * D_ + col];
    }
    #pragma unroll
    for (int mf = 0; mf < 4; ++mf) {
      #pragma unroll
      for (int r = 0; r < 4; ++r) {
        int rowl = wr * 64 + mf * 16 + quad * 4 + r;
        float ms = psum[rowl][0] + psum[rowl][1] + psum[rowl][2] + psum[rowl][3];
        float mq = psq[rowl][0]  + psq[rowl][1]  + psq[rowl][2]  + psq[rowl][3];
        float mean = ms * (1.f / D_);
        float var  = mq * (1.f / D_) - mean * mean;
        float rstd = rsqrtf(var + 1e-5f);
        size_t rbase = (size_t)(m0 + rowl) * 512;
        #pragma unroll
        for (int nf = 0; nf < 8; ++nf) {
          int col = wc * 128 + nf * 16 + l16;
          aout[rbase + col] = f2bf((acc[mf][nf][r] - mean) * rstd * gv[nf] + bv[nf]);
        }
      }
    }
  }
  asm volatile("s_waitcnt vmcnt(0)" ::: "memory");  // drain stray ring prefetches
}

extern "C" void kernel_launch(void* const* d_in, const int* in_sizes, int n_in,
                              void* d_out, int out_size, void* d_ws, size_t ws_size,
                              hipStream_t stream) {
  const float* emb_input  = (const float*)d_in[0];
  const float* dis_input  = (const float*)d_in[1];
  const float* torsion    = (const float*)d_in[2];
  const float* emb_sel_W  = (const float*)d_in[5];
  const float* emb_sel_b  = (const float*)d_in[6];
  const float* emb_ln_g   = (const float*)d_in[7];
  const float* emb_ln_b   = (const float*)d_in[8];
  const float* emb_w1     = (const float*)d_in[9];
  const float* emb_b1     = (const float*)d_in[10];
  const float* emb_w2     = (const float*)d_in[11];
  const float* emb_b2     = (const float*)d_in[12];
  const float* dis_sel_W  = (const float*)d_in[13];
  const float* dis_sel_b  = (const float*)d_in[14];
  const float* dis_ln1_g  = (const float*)d_in[15];
  const float* dis_ln1_b  = (const float*)d_in[16];
  const float* dis_attn_W = (const float*)d_in[17];
  const float* dis_attn_b = (const float*)d_in[18];
  const float* dis_ln2_g  = (const float*)d_in[19];
  const float* dis_ln2_b  = (const float*)d_in[20];
  const float* dis_ff1_W  = (const float*)d_in[21];
  const float* dis_ff1_b  = (const float*)d_in[22];
  const float* dis_ff2_W  = (const float*)d_in[23];
  const float* dis_ff2_b  = (const float*)d_in[24];

  // workspace carve (needs ~138 MB)
  char* w = (char*)d_ws;
  float* accE = (float*)w;                 // 16 KB  (B*D sums, only b=0 used)
  float* accD = (float*)(w + 16384);       // 16 KB
  int*   top  = (int*)(w + 32768);         // [embTop0, embTop1, disTop0, disTop1]
  size_t o = 33024;
  unsigned short* w1t   = (unsigned short*)(w + o); o += 524288;   // [512][512] bf16
  unsigned short* w2t   = (unsigned short*)(w + o); o += 524288;
  unsigned short* attnT = (unsigned short*)(w + o); o += 524288;
  unsigned short* ff1T  = (unsigned short*)(w + o); o += 1048576;  // [1024][512]
  unsigned short* ff2T  = (unsigned short*)(w + o); o += 1048576;  // [512][1024]
  unsigned short* Abuf  = (unsigned short*)(w + o); o += (size_t)M_ * D_ * 2;  // 67 MB
  unsigned short* T1    = (unsigned short*)(w + o); o += (size_t)M_ * D_ * 2;  // 67 MB

  float* outEmb = (float*)d_out;
  float* outDis = outEmb + (size_t)M_ * D_;
  // dis branch runs FIRST: emb half of d_out doubles as the [M,1024] bf16 gelu buffer
  unsigned short* Gbuf = (unsigned short*)d_out;

  const int* di0 = top + 2; const int* di1 = top + 3;
  const int* ei0 = top + 0; const int* ei1 = top + 1;

  zero_kernel<<<32, 256, 0, stream>>>(accE, 2 * B_ * D_);
  colmean_kernel<<<dim3(1, 16), 512, 0, stream>>>(emb_input, accE);  // only b=0 needed
  colmean_kernel<<<dim3(8, 16), 512, 0, stream>>>(dis_input, accD);
  top2_kernel<<<1, 128, 0, stream>>>(accE, emb_sel_W, emb_sel_b,
                                     accD, dis_sel_W, dis_sel_b, top);

  // ---- disembodied branch
  // s=0
  wconvert_kernel<<<dim3(16, 16), 256, 0, stream>>>(dis_attn_W, di0, 512, 512, attnT);
  wconvert_kernel<<<dim3(32, 16), 256, 0, stream>>>(dis_ff1_W,  di0, 512, 1024, ff1T);
  wconvert_kernel<<<dim3(16, 32), 256, 0, stream>>>(dis_ff2_W,  di0, 1024, 512, ff2T);
  ln_cast_kernel<<<M_ / 4, 256, 0, stream>>>(dis_input, dis_ln1_g, dis_ln1_b, di0, Abuf);
  gemm_ln_kernel<2, true><<<512, 512, 0, stream>>>(Abuf, attnT, 512, di0, dis_attn_b,
      dis_input, outDis, torsion, accD, dis_ln2_g, dis_ln2_b, di0, T1);
  gemm_kernel<3><<<1024, 512, 0, stream>>>(T1, ff1T, 512, 1024, di0, dis_ff1_b, Gbuf);
  gemm_ln_kernel<4, true><<<512, 512, 0, stream>>>(Gbuf, ff2T, 1024, di0, dis_ff2_b,
      outDis, outDis, nullptr, nullptr, dis_ln1_g, dis_ln1_b, di1, Abuf);
  // s=1
  wconvert_kernel<<<dim3(16, 16), 256, 0, stream>>>(dis_attn_W, di1, 512, 512, attnT);
  wconvert_kernel<<<dim3(32, 16), 256, 0, stream>>>(dis_ff1_W,  di1, 512, 1024, ff1T);
  wconvert_kernel<<<dim3(16, 32), 256, 0, stream>>>(dis_ff2_W,  di1, 1024, 512, ff2T);
  gemm_ln_kernel<2, true><<<512, 512, 0, stream>>>(Abuf, attnT, 512, di1, dis_attn_b,
      outDis, outDis, torsion, accD, dis_ln2_g, dis_ln2_b, di1, T1);
  gemm_kernel<3><<<1024, 512, 0, stream>>>(T1, ff1T, 512, 1024, di1, dis_ff1_b, Gbuf);
  gemm_ln_kernel<4, false><<<512, 512, 0, stream>>>(Gbuf, ff2T, 1024, di1, dis_ff2_b,
      outDis, outDis, nullptr, nullptr, nullptr, nullptr, nullptr, nullptr);

  // ---- embodied branch (emb half of d_out now free)
  // s=0
  wconvert_kernel<<<dim3(16, 16), 256, 0, stream>>>(emb_w1, ei0, 512, 512, w1t);
  wconvert_kernel<<<dim3(16, 16), 256, 0, stream>>>(emb_w2, ei0, 512, 512, w2t);
  ln_cast_kernel<<<M_ / 4, 256, 0, stream>>>(emb_input, emb_ln_g, emb_ln_b, ei0, Abuf);
  gemm_kernel<0><<<512, 512, 0, stream>>>(Abuf, w1t, 512, 512, ei0, emb_b1, T1);
  gemm_ln_kernel<1, true><<<512, 512, 0, stream>>>(T1, w2t, 512, ei0, emb_b2,
      emb_input, outEmb, torsion, nullptr, emb_ln_g, emb_ln_b, ei1, Abuf);
  // s=1
  wconvert_kernel<<<dim3(16, 16), 256, 0, stream>>>(emb_w1, ei1, 512, 512, w1t);
  wconvert_kernel<<<dim3(16, 16), 256, 0, stream>>>(emb_w2, ei1, 512, 512, w2t);
  gemm_kernel<0><<<512, 512, 0, stream>>>(Abuf, w1t, 512, 512, ei1, emb_b1, T1);
  gemm_ln_kernel<1, false><<<512, 512, 0, stream>>>(T1, w2t, 512, ei1, emb_b2,
      outEmb, outEmb, torsion, nullptr, nullptr, nullptr, nullptr, nullptr);
}

// Round 4
// 1598.314 us; speedup vs baseline: 1.2742x; 1.2742x over previous
//
#include <hip/hip_runtime.h>
#include <stdint.h>

#define B_  8
#define S_  8192
#define D_  512
#define NB_ 16
#define M_  (B_*S_)   // 65536 rows

typedef short bf16x8 __attribute__((ext_vector_type(8)));
typedef float f32x4  __attribute__((ext_vector_type(4)));

static __device__ __forceinline__ unsigned short f2bf(float f) {
  unsigned int u = __float_as_uint(f);
  u += 0x7fff + ((u >> 16) & 1);   // RNE
  return (unsigned short)(u >> 16);
}

// fast exact-erf gelu: Abramowitz-Stegun 7.1.26, |err| <= 1.5e-7 (<< bf16 ulp)
static __device__ __forceinline__ float fast_gelu(float v) {
  float x = fabsf(v) * 0.70710678118654752f;
  float t = __builtin_amdgcn_rcpf(1.f + 0.3275911f * x);
  float poly = ((((1.061405429f * t - 1.453152027f) * t + 1.421413741f) * t
                 - 0.284496736f) * t + 0.254829592f) * t;
  float erfx = 1.f - poly * __expf(-x * x);
  return 0.5f * v * (1.f + copysignf(erfx, v));
}

// fast tanh via exp, |err| ~ 2e-7
static __device__ __forceinline__ float fast_tanh(float v) {
  float a = fabsf(v);
  float e = __expf(2.f * a);                       // inf for large a -> r = 1
  float r = 1.f - 2.f * __builtin_amdgcn_rcpf(e + 1.f);
  return copysignf(r, v);
}

// async global->LDS, 16B per lane. LDS dest is wave-uniform base + lane*16.
static __device__ __forceinline__ void async_copy16(const unsigned short* g,
                                                    unsigned short* l) {
  auto* g1 = reinterpret_cast<const __attribute__((address_space(1))) uint32_t*>(
      reinterpret_cast<uintptr_t>(g));
  auto* l3 = reinterpret_cast<__attribute__((address_space(3))) uint32_t*>(
      reinterpret_cast<uintptr_t>(l));
  __builtin_amdgcn_global_load_lds(g1, l3, 16, 0, 0);
}

__global__ __launch_bounds__(256) void zero_kernel(float* p, int n) {
  int i = blockIdx.x * 256 + threadIdx.x;
  if (i < n) p[i] = 0.f;
}

// Column mean accumulate: acc[b*D+d] += sum_{s in block chunk} x[b][s][d]
__global__ __launch_bounds__(512) void colmean_kernel(const float* __restrict__ x,
                                                      float* __restrict__ acc) {
  int b = blockIdx.x, d = threadIdx.x;
  const float* p = x + ((size_t)b * S_ + (size_t)blockIdx.y * 512) * D_ + d;
  float s = 0.f;
  #pragma unroll 8
  for (int i = 0; i < 512; i++) s += p[(size_t)i * D_];
  atomicAdd(&acc[b * D_ + d], s);
}

// wave0: embodied selector, wave1: disembodied. out[0..1]=emb top2, out[2..3]=dis top2
__global__ __launch_bounds__(128) void top2_kernel(const float* __restrict__ embAcc,
                                                   const float* __restrict__ embW,
                                                   const float* __restrict__ embB,
                                                   const float* __restrict__ disAcc,
                                                   const float* __restrict__ disW,
                                                   const float* __restrict__ disB,
                                                   int* __restrict__ out) {
  int wave = threadIdx.x >> 6, lane = threadIdx.x & 63;
  const float* acc = wave ? disAcc : embAcc;
  const float* W   = wave ? disW   : embW;
  const float* bb  = wave ? disB   : embB;
  const float invS = 1.f / (float)S_;
  float logit[NB_];
  for (int nb = 0; nb < NB_; nb++) {
    float s = 0.f;
    for (int d = lane; d < D_; d += 64) s += acc[d] * invS * W[d * NB_ + nb];
    for (int o = 32; o; o >>= 1) s += __shfl_xor(s, o);
    logit[nb] = s + bb[nb];
  }
  if (lane == 0) {
    int i0 = 0;
    for (int i = 1; i < NB_; i++) if (logit[i] > logit[i0]) i0 = i;
    int i1 = (i0 == 0) ? 1 : 0;
    for (int i = 0; i < NB_; i++) if (i != i0 && logit[i] > logit[i1]) i1 = i;
    out[wave * 2 + 0] = i0;
    out[wave * 2 + 1] = i1;
  }
}

// LayerNorm (dynamic block idx for gamma/beta) + cast to bf16. One wave per row.
__global__ __launch_bounds__(256) void ln_cast_kernel(const float* __restrict__ x,
                                                      const float* __restrict__ gB,
                                                      const float* __restrict__ bB,
                                                      const int* __restrict__ idxPtr,
                                                      unsigned short* __restrict__ out) {
  int row  = blockIdx.x * 4 + (threadIdx.x >> 6);
  int lane = threadIdx.x & 63;
  const float4* xr = (const float4*)(x + (size_t)row * D_ + lane * 8);
  float4 v0 = xr[0], v1 = xr[1];
  float s  = v0.x + v0.y + v0.z + v0.w + v1.x + v1.y + v1.z + v1.w;
  float sq = v0.x*v0.x + v0.y*v0.y + v0.z*v0.z + v0.w*v0.w
           + v1.x*v1.x + v1.y*v1.y + v1.z*v1.z + v1.w*v1.w;
  for (int o = 32; o; o >>= 1) { s += __shfl_xor(s, o); sq += __shfl_xor(sq, o); }
  float mean = s * (1.f / D_);
  float var  = sq * (1.f / D_) - mean * mean;
  float rstd = rsqrtf(var + 1e-5f);
  int idx = *idxPtr;
  const float4* g4 = (const float4*)(gB + (size_t)idx * D_ + lane * 8);
  const float4* b4 = (const float4*)(bB + (size_t)idx * D_ + lane * 8);
  float4 g0 = g4[0], g1 = g4[1], c0 = b4[0], c1 = b4[1];
  float xv[8] = {v0.x, v0.y, v0.z, v0.w, v1.x, v1.y, v1.z, v1.w};
  float gv[8] = {g0.x, g0.y, g0.z, g0.w, g1.x, g1.y, g1.z, g1.w};
  float bv[8] = {c0.x, c0.y, c0.z, c0.w, c1.x, c1.y, c1.z, c1.w};
  unsigned short o8[8] __attribute__((aligned(16)));
  #pragma unroll
  for (int k = 0; k < 8; k++) o8[k] = f2bf((xv[k] - mean) * rstd * gv[k] + bv[k]);
  *(uint4*)(out + (size_t)row * D_ + lane * 8) = *(const uint4*)o8;
}

// Gather selected block's weight [K,N] f32 -> transposed bf16 dst[N][K] (LDS tiled)
__global__ __launch_bounds__(256) void wconvert_kernel(const float* __restrict__ srcAll,
                                                       const int* __restrict__ idxPtr,
                                                       int K, int N,
                                                       unsigned short* __restrict__ dst) {
  __shared__ float t[32][33];
  int idx = *idxPtr;
  const float* src = srcAll + (size_t)idx * K * N;
  int k0 = blockIdx.y * 32, n0 = blockIdx.x * 32;
  int tid = threadIdx.x;
  int kl = tid >> 5, nl = tid & 31;  // kl in 0..7
  #pragma unroll
  for (int r = 0; r < 4; r++)
    t[kl + r * 8][nl] = src[(size_t)(k0 + kl + r * 8) * N + n0 + nl];
  __syncthreads();
  #pragma unroll
  for (int r = 0; r < 4; r++)
    dst[(size_t)(n0 + kl + r * 8) * K + k0 + nl] = f2bf(t[nl][kl + r * 8]);
}

// ---------------------------------------------------------------------------
// R4: occupancy-first GEMM. C[M,N] = A[M,K](bf16) @ Bt[N,K](bf16)^T.
// 128x128 tile, 4 waves (2x2, per-wave 64x64, acc[4][4] = 64 regs), BK=32,
// ring depth 3 -> LDS 48 KiB -> 3 blocks/CU; __launch_bounds__(256,3) caps
// VGPR for 3 waves/SIMD (R3 counters showed 1 blk/CU + 2 w/SIMD = latency-
// bound: MfmaUtil 14%, HBM 12%, Occ 22%). Schedule keeps R2's counted-vmcnt
// ring (4 loads/tile; stage(k+2); vmcnt(8) == tile-k resident) + XOR segment
// swizzle (phys slot p of row r holds seg p^((r>>1)&3), pre-swizzled global
// source, rule #21) + s_setprio around the MFMA cluster.
// EPI 0: bout = bf16(tanh(acc+bias))                         (emb gemm1)
// EPI 1: fout = hin + (acc+bias)*(1+0.1*torsion)*0.3         (emb gemm2)
// EPI 2: fout = hin + 0.5*((acc+bias+0.2*delayed)*(1+0.05*torsion))  (dis attn)
// EPI 3: bout = bf16(gelu_exact(acc+bias))                   (dis ff1)
// EPI 4: fout = hin + 0.5*(acc+bias)                         (dis ff2)
template<int EPI>
__global__ __launch_bounds__(256, 3) void gemm_kernel(const unsigned short* __restrict__ A,
                                                      const unsigned short* __restrict__ Bt,
                                                      int K, int N,
                                                      const int* __restrict__ idxPtr,
                                                      const float* __restrict__ biasBase,
                                                      const float* __restrict__ hin,
                                                      float* __restrict__ fout,
                                                      unsigned short* __restrict__ bout,
                                                      const float* __restrict__ torsion,
                                                      const float* __restrict__ dAcc) {
  __shared__ __align__(16) unsigned short lds[3][2][4096];  // ring slot: A/B 128rows x 32cols
  const int tid  = threadIdx.x;
  const int wid  = tid >> 6, lane = tid & 63;
  const int quad = lane >> 4, l16 = lane & 15;
  const int wm = (wid >> 1) * 64, wn = (wid & 1) * 64;

  // XCD-aware tile swizzle (grids 2048/4096, %8==0): XCD x owns contiguous
  // M-range so its L2 keeps the A rows across the N-tiles.
  const int nT  = N >> 7;                 // 4 or 8 n-tiles
  const int lgn = (nT == 4) ? 2 : 3;
  const int perX = gridDim.x >> 3;
  const int tile = ((int)blockIdx.x & 7) * perX + ((int)blockIdx.x >> 3);
  const int m0 = (tile >> lgn) << 7;
  const int n0 = (tile & (nT - 1)) << 7;

  // staging: thread t covers 16B of row t/4 (per 64-row half). HW writes LDS
  // linearly at slot (t&3); global src holds logical seg (t&3)^sw(row),
  // sw(r) = (r>>1)&3 = (t>>3)&3 (invariant to +64).
  const int srow = tid >> 2;
  const int scol = (((tid & 3) ^ ((tid >> 3) & 3)) * 8);
  const unsigned short* Ag0 = A  + (size_t)(m0 + srow) * K + scol;
  const unsigned short* Ag1 = Ag0 + (size_t)64 * K;
  const unsigned short* Bg0 = Bt + (size_t)(n0 + srow) * K + scol;
  const unsigned short* Bg1 = Bg0 + (size_t)64 * K;

  auto stage = [&](int kt, int slot) {
    async_copy16(Ag0 + (size_t)kt * 32, &lds[slot][0][tid * 8]);
    async_copy16(Ag1 + (size_t)kt * 32, &lds[slot][0][2048 + tid * 8]);
    async_copy16(Bg0 + (size_t)kt * 32, &lds[slot][1][tid * 8]);
    async_copy16(Bg1 + (size_t)kt * 32, &lds[slot][1][2048 + tid * 8]);
  };

  f32x4 acc[4][4] = {};
  const int nK = K >> 5;

  stage(0, 0);
  stage(1, 1);

  // fragment rows are 16*m + l16 -> swizzle term depends on l16 only
  const int rsw  = (l16 >> 1) & 3;
  const int aoff = (wm + l16) * 32 + ((quad ^ rsw) * 8);
  const int boff = (wn + l16) * 32 + ((quad ^ rsw) * 8);

  for (int k = 0; k < nK; ++k) {
    const int cur = k % 3;
    const int nxt = (k + 2) % 3;
    const int kn  = (k + 2 < nK) ? (k + 2) : 0;   // clamp keeps counts uniform
    stage(kn, nxt);
    // outstanding newer than tile k: tile k+1 (4) + tile k+2 (4) = 8
    asm volatile("s_waitcnt vmcnt(8)" ::: "memory");
    asm volatile("s_barrier" ::: "memory");       // tile k visible to all waves

    const unsigned short* Ab = &lds[cur][0][aoff];
    const unsigned short* Bb = &lds[cur][1][boff];
    bf16x8 af[4], bfr[4];
    #pragma unroll
    for (int i = 0; i < 4; ++i) af[i]  = *(const bf16x8*)(Ab + i * 512);
    #pragma unroll
    for (int j = 0; j < 4; ++j) bfr[j] = *(const bf16x8*)(Bb + j * 512);
    __builtin_amdgcn_s_setprio(1);
    #pragma unroll
    for (int i = 0; i < 4; ++i)
      #pragma unroll
      for (int j = 0; j < 4; ++j)
        acc[i][j] = __builtin_amdgcn_mfma_f32_16x16x32_bf16(af[i], bfr[j], acc[i][j], 0, 0, 0);
    __builtin_amdgcn_s_setprio(0);
    // all reads of buf[cur] done -> next iter may stage into it
    asm volatile("s_barrier" ::: "memory");
  }

  const int idx = *idxPtr;
  const float* bias = biasBase + (size_t)idx * N;
  const float invS = 1.f / (float)S_;
  #pragma unroll
  for (int i = 0; i < 4; ++i) {
    int rowb = m0 + wm + i * 16 + quad * 4;
    #pragma unroll
    for (int j = 0; j < 4; ++j) {
      int col = n0 + wn + j * 16 + l16;
      float bc = bias[col];
      #pragma unroll
      for (int r = 0; r < 4; ++r) {
        int row = rowb + r;
        size_t off = (size_t)row * N + col;
        float v = acc[i][j][r] + bc;
        if constexpr (EPI == 0) {
          bout[off] = f2bf(fast_tanh(v));
        } else if constexpr (EPI == 1) {
          int b = row >> 13;  // S = 8192
          float t = 1.f + 0.1f * torsion[b * D_ + col];
          fout[off] = hin[off] + v * t * 0.3f;
        } else if constexpr (EPI == 2) {
          int b = row >> 13;
          float t = 1.f + 0.05f * torsion[b * D_ + col];
          float h1 = (v + 0.2f * dAcc[b * D_ + col] * invS) * t;
          fout[off] = hin[off] + 0.5f * h1;
        } else if constexpr (EPI == 3) {
          bout[off] = f2bf(fast_gelu(v));
        } else {
          fout[off] = hin[off] + 0.5f * v;
        }
      }
    }
  }
  asm volatile("s_waitcnt vmcnt(0)" ::: "memory");  // drain stray ring prefetches
}

extern "C" void kernel_launch(void* const* d_in, const int* in_sizes, int n_in,
                              void* d_out, int out_size, void* d_ws, size_t ws_size,
                              hipStream_t stream) {
  const float* emb_input  = (const float*)d_in[0];
  const float* dis_input  = (const float*)d_in[1];
  const float* torsion    = (const float*)d_in[2];
  const float* emb_sel_W  = (const float*)d_in[5];
  const float* emb_sel_b  = (const float*)d_in[6];
  const float* emb_ln_g   = (const float*)d_in[7];
  const float* emb_ln_b   = (const float*)d_in[8];
  const float* emb_w1     = (const float*)d_in[9];
  const float* emb_b1     = (const float*)d_in[10];
  const float* emb_w2     = (const float*)d_in[11];
  const float* emb_b2     = (const float*)d_in[12];
  const float* dis_sel_W  = (const float*)d_in[13];
  const float* dis_sel_b  = (const float*)d_in[14];
  const float* dis_ln1_g  = (const float*)d_in[15];
  const float* dis_ln1_b  = (const float*)d_in[16];
  const float* dis_attn_W = (const float*)d_in[17];
  const float* dis_attn_b = (const float*)d_in[18];
  const float* dis_ln2_g  = (const float*)d_in[19];
  const float* dis_ln2_b  = (const float*)d_in[20];
  const float* dis_ff1_W  = (const float*)d_in[21];
  const float* dis_ff1_b  = (const float*)d_in[22];
  const float* dis_ff2_W  = (const float*)d_in[23];
  const float* dis_ff2_b  = (const float*)d_in[24];

  // workspace carve (needs ~138 MB)
  char* w = (char*)d_ws;
  float* accE = (float*)w;                 // 16 KB  (B*D sums, only b=0 used)
  float* accD = (float*)(w + 16384);       // 16 KB
  int*   top  = (int*)(w + 32768);         // [embTop0, embTop1, disTop0, disTop1]
  size_t o = 33024;
  unsigned short* w1t   = (unsigned short*)(w + o); o += 524288;   // [512][512] bf16
  unsigned short* w2t   = (unsigned short*)(w + o); o += 524288;
  unsigned short* attnT = (unsigned short*)(w + o); o += 524288;
  unsigned short* ff1T  = (unsigned short*)(w + o); o += 1048576;  // [1024][512]
  unsigned short* ff2T  = (unsigned short*)(w + o); o += 1048576;  // [512][1024]
  unsigned short* Abuf  = (unsigned short*)(w + o); o += (size_t)M_ * D_ * 2;  // 67 MB
  unsigned short* T1    = (unsigned short*)(w + o); o += (size_t)M_ * D_ * 2;  // 67 MB

  float* outEmb = (float*)d_out;
  float* outDis = outEmb + (size_t)M_ * D_;
  // dis branch runs FIRST: emb half of d_out doubles as the [M,1024] bf16 gelu buffer
  unsigned short* Gbuf = (unsigned short*)d_out;

  zero_kernel<<<32, 256, 0, stream>>>(accE, 2 * B_ * D_);
  colmean_kernel<<<dim3(1, 16), 512, 0, stream>>>(emb_input, accE);  // only b=0 needed
  colmean_kernel<<<dim3(8, 16), 512, 0, stream>>>(dis_input, accD);
  top2_kernel<<<1, 128, 0, stream>>>(accE, emb_sel_W, emb_sel_b,
                                     accD, dis_sel_W, dis_sel_b, top);

  // ---- disembodied branch (2 selected blocks, sequential)
  for (int s = 0; s < 2; s++) {
    const int* di = top + 2 + s;
    const float* dh = (s == 0) ? dis_input : outDis;
    wconvert_kernel<<<dim3(16, 16), 256, 0, stream>>>(dis_attn_W, di, 512, 512, attnT);
    wconvert_kernel<<<dim3(32, 16), 256, 0, stream>>>(dis_ff1_W,  di, 512, 1024, ff1T);
    wconvert_kernel<<<dim3(16, 32), 256, 0, stream>>>(dis_ff2_W,  di, 1024, 512, ff2T);
    ln_cast_kernel<<<M_ / 4, 256, 0, stream>>>(dh, dis_ln1_g, dis_ln1_b, di, Abuf);
    gemm_kernel<2><<<2048, 256, 0, stream>>>(Abuf, attnT, 512, 512, di,
        dis_attn_b, dh, outDis, nullptr, torsion, accD);
    ln_cast_kernel<<<M_ / 4, 256, 0, stream>>>(outDis, dis_ln2_g, dis_ln2_b, di, Abuf);
    gemm_kernel<3><<<4096, 256, 0, stream>>>(Abuf, ff1T, 512, 1024, di,
        dis_ff1_b, nullptr, nullptr, Gbuf, nullptr, nullptr);
    gemm_kernel<4><<<2048, 256, 0, stream>>>(Gbuf, ff2T, 1024, 512, di,
        dis_ff2_b, outDis, outDis, nullptr, nullptr, nullptr);
  }

  // ---- embodied branch (overwrites emb half of d_out, which is now free)
  for (int s = 0; s < 2; s++) {
    const int* ei = top + s;
    const float* h = (s == 0) ? emb_input : outEmb;
    wconvert_kernel<<<dim3(16, 16), 256, 0, stream>>>(emb_w1, ei, 512, 512, w1t);
    wconvert_kernel<<<dim3(16, 16), 256, 0, stream>>>(emb_w2, ei, 512, 512, w2t);
    ln_cast_kernel<<<M_ / 4, 256, 0, stream>>>(h, emb_ln_g, emb_ln_b, ei, Abuf);
    gemm_kernel<0><<<2048, 256, 0, stream>>>(Abuf, w1t, 512, 512, ei,
        emb_b1, nullptr, nullptr, T1, nullptr, nullptr);
    gemm_kernel<1><<<2048, 256, 0, stream>>>(T1, w2t, 512, 512, ei,
        emb_b2, h, outEmb, nullptr, torsion, nullptr);
  }
}

// Round 5
// 1581.452 us; speedup vs baseline: 1.2878x; 1.0107x over previous
//
#include <hip/hip_runtime.h>
#include <stdint.h>

#define B_  8
#define S_  8192
#define D_  512
#define NB_ 16
#define M_  (B_*S_)   // 65536 rows

typedef short bf16x8 __attribute__((ext_vector_type(8)));
typedef float f32x4  __attribute__((ext_vector_type(4)));

static __device__ __forceinline__ unsigned short f2bf(float f) {
  unsigned int u = __float_as_uint(f);
  u += 0x7fff + ((u >> 16) & 1);   // RNE
  return (unsigned short)(u >> 16);
}

// fast exact-erf gelu: Abramowitz-Stegun 7.1.26, |err| <= 1.5e-7 (<< bf16 ulp)
static __device__ __forceinline__ float fast_gelu(float v) {
  float x = fabsf(v) * 0.70710678118654752f;
  float t = __builtin_amdgcn_rcpf(1.f + 0.3275911f * x);
  float poly = ((((1.061405429f * t - 1.453152027f) * t + 1.421413741f) * t
                 - 0.284496736f) * t + 0.254829592f) * t;
  float erfx = 1.f - poly * __expf(-x * x);
  return 0.5f * v * (1.f + copysignf(erfx, v));
}

// fast tanh via exp, |err| ~ 2e-7
static __device__ __forceinline__ float fast_tanh(float v) {
  float a = fabsf(v);
  float e = __expf(2.f * a);                       // inf for large a -> r = 1
  float r = 1.f - 2.f * __builtin_amdgcn_rcpf(e + 1.f);
  return copysignf(r, v);
}

// async global->LDS, 16B per lane. LDS dest is wave-uniform base + lane*16.
static __device__ __forceinline__ void async_copy16(const unsigned short* g,
                                                    unsigned short* l) {
  auto* g1 = reinterpret_cast<const __attribute__((address_space(1))) uint32_t*>(
      reinterpret_cast<uintptr_t>(g));
  auto* l3 = reinterpret_cast<__attribute__((address_space(3))) uint32_t*>(
      reinterpret_cast<uintptr_t>(l));
  __builtin_amdgcn_global_load_lds(g1, l3, 16, 0, 0);
}

__global__ __launch_bounds__(256) void zero_kernel(float* p, int n) {
  int i = blockIdx.x * 256 + threadIdx.x;
  if (i < n) p[i] = 0.f;
}

// Column mean accumulate: acc[b*D+d] += sum_{s in block chunk} x[b][s][d]
__global__ __launch_bounds__(512) void colmean_kernel(const float* __restrict__ x,
                                                      float* __restrict__ acc) {
  int b = blockIdx.x, d = threadIdx.x;
  const float* p = x + ((size_t)b * S_ + (size_t)blockIdx.y * 512) * D_ + d;
  float s = 0.f;
  #pragma unroll 8
  for (int i = 0; i < 512; i++) s += p[(size_t)i * D_];
  atomicAdd(&acc[b * D_ + d], s);
}

// wave0: embodied selector, wave1: disembodied. out[0..1]=emb top2, out[2..3]=dis top2
__global__ __launch_bounds__(128) void top2_kernel(const float* __restrict__ embAcc,
                                                   const float* __restrict__ embW,
                                                   const float* __restrict__ embB,
                                                   const float* __restrict__ disAcc,
                                                   const float* __restrict__ disW,
                                                   const float* __restrict__ disB,
                                                   int* __restrict__ out) {
  int wave = threadIdx.x >> 6, lane = threadIdx.x & 63;
  const float* acc = wave ? disAcc : embAcc;
  const float* W   = wave ? disW   : embW;
  const float* bb  = wave ? disB   : embB;
  const float invS = 1.f / (float)S_;
  float logit[NB_];
  for (int nb = 0; nb < NB_; nb++) {
    float s = 0.f;
    for (int d = lane; d < D_; d += 64) s += acc[d] * invS * W[d * NB_ + nb];
    for (int o = 32; o; o >>= 1) s += __shfl_xor(s, o);
    logit[nb] = s + bb[nb];
  }
  if (lane == 0) {
    int i0 = 0;
    for (int i = 1; i < NB_; i++) if (logit[i] > logit[i0]) i0 = i;
    int i1 = (i0 == 0) ? 1 : 0;
    for (int i = 0; i < NB_; i++) if (i != i0 && logit[i] > logit[i1]) i1 = i;
    out[wave * 2 + 0] = i0;
    out[wave * 2 + 1] = i1;
  }
}

// LayerNorm (dynamic block idx for gamma/beta) + cast to bf16. One wave per row.
__global__ __launch_bounds__(256) void ln_cast_kernel(const float* __restrict__ x,
                                                      const float* __restrict__ gB,
                                                      const float* __restrict__ bB,
                                                      const int* __restrict__ idxPtr,
                                                      unsigned short* __restrict__ out) {
  int row  = blockIdx.x * 4 + (threadIdx.x >> 6);
  int lane = threadIdx.x & 63;
  const float4* xr = (const float4*)(x + (size_t)row * D_ + lane * 8);
  float4 v0 = xr[0], v1 = xr[1];
  float s  = v0.x + v0.y + v0.z + v0.w + v1.x + v1.y + v1.z + v1.w;
  float sq = v0.x*v0.x + v0.y*v0.y + v0.z*v0.z + v0.w*v0.w
           + v1.x*v1.x + v1.y*v1.y + v1.z*v1.z + v1.w*v1.w;
  for (int o = 32; o; o >>= 1) { s += __shfl_xor(s, o); sq += __shfl_xor(sq, o); }
  float mean = s * (1.f / D_);
  float var  = sq * (1.f / D_) - mean * mean;
  float rstd = rsqrtf(var + 1e-5f);
  int idx = *idxPtr;
  const float4* g4 = (const float4*)(gB + (size_t)idx * D_ + lane * 8);
  const float4* b4 = (const float4*)(bB + (size_t)idx * D_ + lane * 8);
  float4 g0 = g4[0], g1 = g4[1], c0 = b4[0], c1 = b4[1];
  float xv[8] = {v0.x, v0.y, v0.z, v0.w, v1.x, v1.y, v1.z, v1.w};
  float gv[8] = {g0.x, g0.y, g0.z, g0.w, g1.x, g1.y, g1.z, g1.w};
  float bv[8] = {c0.x, c0.y, c0.z, c0.w, c1.x, c1.y, c1.z, c1.w};
  unsigned short o8[8] __attribute__((aligned(16)));
  #pragma unroll
  for (int k = 0; k < 8; k++) o8[k] = f2bf((xv[k] - mean) * rstd * gv[k] + bv[k]);
  *(uint4*)(out + (size_t)row * D_ + lane * 8) = *(const uint4*)o8;
}

// Gather selected block's weight [K,N] f32 -> transposed bf16 dst[N][K] (LDS tiled)
__global__ __launch_bounds__(256) void wconvert_kernel(const float* __restrict__ srcAll,
                                                       const int* __restrict__ idxPtr,
                                                       int K, int N,
                                                       unsigned short* __restrict__ dst) {
  __shared__ float t[32][33];
  int idx = *idxPtr;
  const float* src = srcAll + (size_t)idx * K * N;
  int k0 = blockIdx.y * 32, n0 = blockIdx.x * 32;
  int tid = threadIdx.x;
  int kl = tid >> 5, nl = tid & 31;  // kl in 0..7
  #pragma unroll
  for (int r = 0; r < 4; r++)
    t[kl + r * 8][nl] = src[(size_t)(k0 + kl + r * 8) * N + n0 + nl];
  __syncthreads();
  #pragma unroll
  for (int r = 0; r < 4; r++)
    dst[(size_t)(n0 + kl + r * 8) * K + k0 + nl] = f2bf(t[nl][kl + r * 8]);
}

// ---------------------------------------------------------------------------
// R5: wave-stream-first GEMM. 128x128 tile, BK=32, ring-3 (48 KiB LDS ->
// 3 blk/CU), but 8 WAVES per block (2Mx4N, per-wave 64x32 out, acc[4][2]=32
// regs) with __launch_bounds__(512,6): 24 waves/CU = 6/SIMD — double R4's
// independent instruction streams per SIMD at identical LDS/traffic (R4's
// 3 blk x 4 waves = 3/SIMD barely beat R2 -> block count alone wasn't it;
// theory: lockstep barrier stalls need more decoupled wave streams to fill).
// Staging: 2 global_load_lds per thread per K-tile; counted vmcnt 4/2/0 with
// peeled tail (no clamped re-loads). XOR segment swizzle + XCD tile swizzle
// + setprio as before.
// EPI 0: bout = bf16(tanh(acc+bias))                         (emb gemm1)
// EPI 1: fout = hin + (acc+bias)*(1+0.1*torsion)*0.3         (emb gemm2)
// EPI 2: fout = hin + 0.5*((acc+bias+0.2*delayed)*(1+0.05*torsion))  (dis attn)
// EPI 3: bout = bf16(gelu_exact(acc+bias))                   (dis ff1)
// EPI 4: fout = hin + 0.5*(acc+bias)                         (dis ff2)
template<int EPI>
__global__ __launch_bounds__(512, 6) void gemm_kernel(const unsigned short* __restrict__ A,
                                                      const unsigned short* __restrict__ Bt,
                                                      int K, int N,
                                                      const int* __restrict__ idxPtr,
                                                      const float* __restrict__ biasBase,
                                                      const float* __restrict__ hin,
                                                      float* __restrict__ fout,
                                                      unsigned short* __restrict__ bout,
                                                      const float* __restrict__ torsion,
                                                      const float* __restrict__ dAcc) {
  __shared__ __align__(16) unsigned short ring[3][2][4096];  // slot: A/B 128rows x 32cols
  const int tid  = threadIdx.x;
  const int wid  = tid >> 6, lane = tid & 63;
  const int quad = lane >> 4, l16 = lane & 15;
  const int wr = wid >> 2, wc = wid & 3;   // 2M x 4N waves; per-wave 64 rows x 32 cols

  // XCD-aware tile swizzle (grids 2048/4096, %8==0): XCD x owns a contiguous
  // M-range, n fastest within -> concurrent blocks share A rows in its L2.
  const int nT  = N >> 7;                 // 4 or 8 n-tiles
  const int lgn = (nT == 4) ? 2 : 3;
  const int perX = gridDim.x >> 3;
  const int tile = ((int)blockIdx.x & 7) * perX + ((int)blockIdx.x >> 3);
  const int m0 = (tile >> lgn) << 7;
  const int n0 = (tile & (nT - 1)) << 7;

  // staging: thread t (0..511) covers 16B of row t/4. HW writes LDS linearly
  // at slot (t&3); global src holds logical seg (t&3)^sw(row), sw(r)=(r>>1)&3
  // = (t>>3)&3.
  const int srow = tid >> 2;
  const int scol = (((tid & 3) ^ ((tid >> 3) & 3)) * 8);
  const unsigned short* Ag = A  + (size_t)(m0 + srow) * K + scol;
  const unsigned short* Bg = Bt + (size_t)(n0 + srow) * K + scol;

  auto stage = [&](int kt, int slot) {
    async_copy16(Ag + (size_t)kt * 32, &ring[slot][0][tid * 8]);
    async_copy16(Bg + (size_t)kt * 32, &ring[slot][1][tid * 8]);
  };

  f32x4 acc[4][2] = {};
  const int nK = K >> 5;

  stage(0, 0);
  stage(1, 1);

  // fragment rows are 16*m + l16 -> swizzle term depends on l16 only
  const int rsw  = (l16 >> 1) & 3;
  const int aoff = (wr * 64 + l16) * 32 + ((quad ^ rsw) * 8);
  const int boff = (wc * 32 + l16) * 32 + ((quad ^ rsw) * 8);

#define KSTEP(CUR, VM) do {                                                     \
    asm volatile("s_waitcnt vmcnt(" VM ")" ::: "memory");                       \
    asm volatile("s_barrier" ::: "memory");                                     \
    const unsigned short* Ab = &ring[(CUR)][0][0] + aoff;                       \
    const unsigned short* Bb = &ring[(CUR)][1][0] + boff;                       \
    bf16x8 af[4], bfr[2];                                                       \
    _Pragma("unroll")                                                           \
    for (int i_ = 0; i_ < 4; ++i_) af[i_]  = *(const bf16x8*)(Ab + i_ * 512);   \
    _Pragma("unroll")                                                           \
    for (int j_ = 0; j_ < 2; ++j_) bfr[j_] = *(const bf16x8*)(Bb + j_ * 512);   \
    __builtin_amdgcn_s_setprio(1);                                              \
    _Pragma("unroll")                                                           \
    for (int i_ = 0; i_ < 4; ++i_)                                              \
      _Pragma("unroll")                                                         \
      for (int j_ = 0; j_ < 2; ++j_)                                            \
        acc[i_][j_] = __builtin_amdgcn_mfma_f32_16x16x32_bf16(af[i_], bfr[j_],  \
                                                              acc[i_][j_], 0, 0, 0); \
    __builtin_amdgcn_s_setprio(0);                                              \
    asm volatile("s_barrier" ::: "memory");                                     \
  } while (0)

  // main loop: stage tile k+2, consume tile k. Outstanding at wait: 3 tiles
  // x 2 loads = 6 -> vmcnt(4) drains tile k. Peeled tail: vmcnt(2), vmcnt(0).
  int cur = 0, nxt = 2;
  for (int k = 0; k + 2 < nK; ++k) {
    stage(k + 2, nxt);
    KSTEP(cur, "4");
    cur = (cur == 2) ? 0 : cur + 1;
    nxt = (nxt == 2) ? 0 : nxt + 1;
  }
  KSTEP(cur, "2");
  cur = (cur == 2) ? 0 : cur + 1;
  KSTEP(cur, "0");
#undef KSTEP

  const int idx = *idxPtr;
  const float* bias = biasBase + (size_t)idx * N;
  const int bcn = m0 >> 13;               // batch index, uniform per block (S=8192)
  const float invS = 1.f / (float)S_;
  float bc[2], tv[2], dv[2];
  #pragma unroll
  for (int j = 0; j < 2; ++j) {
    int col = n0 + wc * 32 + j * 16 + l16;
    bc[j] = bias[col];
    if constexpr (EPI == 1) tv[j] = 1.f + 0.1f  * torsion[bcn * D_ + col];
    if constexpr (EPI == 2) tv[j] = 1.f + 0.05f * torsion[bcn * D_ + col];
    if constexpr (EPI == 2) dv[j] = 0.2f * dAcc[bcn * D_ + col] * invS;
  }
  #pragma unroll
  for (int i = 0; i < 4; ++i) {
    int rowb = m0 + wr * 64 + i * 16 + quad * 4;
    #pragma unroll
    for (int j = 0; j < 2; ++j) {
      int col = n0 + wc * 32 + j * 16 + l16;
      #pragma unroll
      for (int r = 0; r < 4; ++r) {
        size_t off = (size_t)(rowb + r) * N + col;
        float v = acc[i][j][r] + bc[j];
        if constexpr (EPI == 0) {
          bout[off] = f2bf(fast_tanh(v));
        } else if constexpr (EPI == 1) {
          fout[off] = hin[off] + v * tv[j] * 0.3f;
        } else if constexpr (EPI == 2) {
          fout[off] = hin[off] + 0.5f * ((v + dv[j]) * tv[j]);
        } else if constexpr (EPI == 3) {
          bout[off] = f2bf(fast_gelu(v));
        } else {
          fout[off] = hin[off] + 0.5f * v;
        }
      }
    }
  }
}

extern "C" void kernel_launch(void* const* d_in, const int* in_sizes, int n_in,
                              void* d_out, int out_size, void* d_ws, size_t ws_size,
                              hipStream_t stream) {
  const float* emb_input  = (const float*)d_in[0];
  const float* dis_input  = (const float*)d_in[1];
  const float* torsion    = (const float*)d_in[2];
  const float* emb_sel_W  = (const float*)d_in[5];
  const float* emb_sel_b  = (const float*)d_in[6];
  const float* emb_ln_g   = (const float*)d_in[7];
  const float* emb_ln_b   = (const float*)d_in[8];
  const float* emb_w1     = (const float*)d_in[9];
  const float* emb_b1     = (const float*)d_in[10];
  const float* emb_w2     = (const float*)d_in[11];
  const float* emb_b2     = (const float*)d_in[12];
  const float* dis_sel_W  = (const float*)d_in[13];
  const float* dis_sel_b  = (const float*)d_in[14];
  const float* dis_ln1_g  = (const float*)d_in[15];
  const float* dis_ln1_b  = (const float*)d_in[16];
  const float* dis_attn_W = (const float*)d_in[17];
  const float* dis_attn_b = (const float*)d_in[18];
  const float* dis_ln2_g  = (const float*)d_in[19];
  const float* dis_ln2_b  = (const float*)d_in[20];
  const float* dis_ff1_W  = (const float*)d_in[21];
  const float* dis_ff1_b  = (const float*)d_in[22];
  const float* dis_ff2_W  = (const float*)d_in[23];
  const float* dis_ff2_b  = (const float*)d_in[24];

  // workspace carve (needs ~138 MB)
  char* w = (char*)d_ws;
  float* accE = (float*)w;                 // 16 KB  (B*D sums, only b=0 used)
  float* accD = (float*)(w + 16384);       // 16 KB
  int*   top  = (int*)(w + 32768);         // [embTop0, embTop1, disTop0, disTop1]
  size_t o = 33024;
  unsigned short* w1t   = (unsigned short*)(w + o); o += 524288;   // [512][512] bf16
  unsigned short* w2t   = (unsigned short*)(w + o); o += 524288;
  unsigned short* attnT = (unsigned short*)(w + o); o += 524288;
  unsigned short* ff1T  = (unsigned short*)(w + o); o += 1048576;  // [1024][512]
  unsigned short* ff2T  = (unsigned short*)(w + o); o += 1048576;  // [512][1024]
  unsigned short* Abuf  = (unsigned short*)(w + o); o += (size_t)M_ * D_ * 2;  // 67 MB
  unsigned short* T1    = (unsigned short*)(w + o); o += (size_t)M_ * D_ * 2;  // 67 MB

  float* outEmb = (float*)d_out;
  float* outDis = outEmb + (size_t)M_ * D_;
  // dis branch runs FIRST: emb half of d_out doubles as the [M,1024] bf16 gelu buffer
  unsigned short* Gbuf = (unsigned short*)d_out;

  zero_kernel<<<32, 256, 0, stream>>>(accE, 2 * B_ * D_);
  colmean_kernel<<<dim3(1, 16), 512, 0, stream>>>(emb_input, accE);  // only b=0 needed
  colmean_kernel<<<dim3(8, 16), 512, 0, stream>>>(dis_input, accD);
  top2_kernel<<<1, 128, 0, stream>>>(accE, emb_sel_W, emb_sel_b,
                                     accD, dis_sel_W, dis_sel_b, top);

  // ---- disembodied branch (2 selected blocks, sequential)
  for (int s = 0; s < 2; s++) {
    const int* di = top + 2 + s;
    const float* dh = (s == 0) ? dis_input : outDis;
    wconvert_kernel<<<dim3(16, 16), 256, 0, stream>>>(dis_attn_W, di, 512, 512, attnT);
    wconvert_kernel<<<dim3(32, 16), 256, 0, stream>>>(dis_ff1_W,  di, 512, 1024, ff1T);
    wconvert_kernel<<<dim3(16, 32), 256, 0, stream>>>(dis_ff2_W,  di, 1024, 512, ff2T);
    ln_cast_kernel<<<M_ / 4, 256, 0, stream>>>(dh, dis_ln1_g, dis_ln1_b, di, Abuf);
    gemm_kernel<2><<<2048, 512, 0, stream>>>(Abuf, attnT, 512, 512, di,
        dis_attn_b, dh, outDis, nullptr, torsion, accD);
    ln_cast_kernel<<<M_ / 4, 256, 0, stream>>>(outDis, dis_ln2_g, dis_ln2_b, di, Abuf);
    gemm_kernel<3><<<4096, 512, 0, stream>>>(Abuf, ff1T, 512, 1024, di,
        dis_ff1_b, nullptr, nullptr, Gbuf, nullptr, nullptr);
    gemm_kernel<4><<<2048, 512, 0, stream>>>(Gbuf, ff2T, 1024, 512, di,
        dis_ff2_b, outDis, outDis, nullptr, nullptr, nullptr);
  }

  // ---- embodied branch (overwrites emb half of d_out, which is now free)
  for (int s = 0; s < 2; s++) {
    const int* ei = top + s;
    const float* h = (s == 0) ? emb_input : outEmb;
    wconvert_kernel<<<dim3(16, 16), 256, 0, stream>>>(emb_w1, ei, 512, 512, w1t);
    wconvert_kernel<<<dim3(16, 16), 256, 0, stream>>>(emb_w2, ei, 512, 512, w2t);
    ln_cast_kernel<<<M_ / 4, 256, 0, stream>>>(h, emb_ln_g, emb_ln_b, ei, Abuf);
    gemm_kernel<0><<<2048, 512, 0, stream>>>(Abuf, w1t, 512, 512, ei,
        emb_b1, nullptr, nullptr, T1, nullptr, nullptr);
    gemm_kernel<1><<<2048, 512, 0, stream>>>(T1, w2t, 512, 512, ei,
        emb_b2, h, outEmb, nullptr, torsion, nullptr);
  }
}